// Round 8
// baseline (850.658 us; speedup 1.0000x reference)
//
#include <hip/hip_runtime.h>
#include <hip/hip_cooperative_groups.h>
#include <math.h>

namespace cg = cooperative_groups;

#define HH 512
#define WW 512
#define NCH 48
#define HWPIX (HH * WW)

#define TW 16            // tile width (pixels)
#define TH 8             // tile height
#define HW_HALO 18       // TW + 2
#define HH_HALO 10       // TH + 2
#define NHALO (HW_HALO * HH_HALO)   // 180 halo pixels
#define PSTRIDE 13       // float4 slots per halo pixel (12 + 1 pad)
#define ASTRIDE 12       // floats per pixel in packed A (9 + 3 pad, 16B-aligned)

#define NTILES 2048

// ---------------------------------------------------------------------------
// Kernel 1: precompute the 9 per-pixel stencil weights from Dt, with
//   border masks, 1/dg and MSQ=0.1 folded in.  Pixel-major packed layout:
//   A[pix*12 + k] multiplies x[h-1+k/3, w-1+k%3]; 3 aligned float4 per pixel.
// ---------------------------------------------------------------------------
__global__ __launch_bounds__(256) void compute_A_kernel(
    const float* __restrict__ Dt, const float* __restrict__ dg,
    float* __restrict__ A) {
  int pix = blockIdx.x * blockDim.x + threadIdx.x;
  int h = pix >> 9;
  int w = pix & (WW - 1);
  int hm = (h == 0) ? HH - 1 : h - 1;
  int hp = (h == HH - 1) ? 0 : h + 1;
  int wm = (w == 0) ? WW - 1 : w - 1;
  int wp = (w == WW - 1) ? 0 : w + 1;

  float aC, cC, bC, cL, bL, cR, bR, aU, bU, aD, bD;
  float bUL, bUR, bDL, bDR;
  {
    int p;
    p = (h * WW + w) * 3;   aC = Dt[p]; cC = Dt[p + 1]; bC = Dt[p + 2];
    p = (h * WW + wm) * 3;  cL = Dt[p + 1]; bL = Dt[p + 2];
    p = (h * WW + wp) * 3;  cR = Dt[p + 1]; bR = Dt[p + 2];
    p = (hm * WW + w) * 3;  aU = Dt[p]; bU = Dt[p + 2];
    p = (hp * WW + w) * 3;  aD = Dt[p]; bD = Dt[p + 2];
    p = (hm * WW + wm) * 3; bUL = Dt[p + 2];
    p = (hm * WW + wp) * 3; bUR = Dt[p + 2];
    p = (hp * WW + wm) * 3; bDL = Dt[p + 2];
    p = (hp * WW + wp) * 3; bDR = Dt[p + 2];
  }

  float A0 = (fabsf(bDL) - bDL + fabsf(bC) - bC) * 0.25f;
  float A1 = (cL + cC - fabsf(bL) - fabsf(bC)) * 0.5f;
  float A2 = (fabsf(bUL) + bUL + fabsf(bC) + bC) * 0.25f;
  float A3 = (aD + aC - fabsf(bD) - fabsf(bC)) * 0.5f;
  float A4 = -(aD + 2.f * aC + aU) * 0.5f
             - (fabsf(bDL) - bDL + fabsf(bUL) + bUL) * 0.25f
             - (fabsf(bDR) + bDR + fabsf(bUR) - bUR) * 0.25f
             + (fabsf(bD) + fabsf(bU) + fabsf(bR) + fabsf(bL) + 2.f * fabsf(bC)) * 0.5f
             - (cR + 2.f * cC + cL) * 0.5f;
  float A5 = (aU + aC - fabsf(bU) - fabsf(bC)) * 0.5f;
  float A6 = (fabsf(bDR) + bDR + fabsf(bC) + bC) * 0.25f;
  float A7 = (cR + cC - fabsf(bR) - fabsf(bC)) * 0.5f;
  float A8 = (fabsf(bUR) - bUR + fabsf(bC) - bC) * 0.25f;

  bool ru = (h > 0), rd = (h < HH - 1), cl = (w > 0), cr = (w < WW - 1);
  if (!(ru && cl)) A0 = 0.f;
  if (!ru)         A1 = 0.f;
  if (!(ru && cr)) A2 = 0.f;
  if (!cl)         A3 = 0.f;
  if (!cr)         A5 = 0.f;
  if (!(rd && cl)) A6 = 0.f;
  if (!rd)         A7 = 0.f;
  if (!(rd && cr)) A8 = 0.f;

  float g = 1.0f / dg[pix];
  float4* Ao = (float4*)A + (size_t)pix * 3;
  Ao[0] = make_float4(A0 * g, A1 * g, A2 * g, A3 * g);
  Ao[1] = make_float4(A4 * g + 0.1f, A5 * g, A6 * g, A7 * g);
  Ao[2] = make_float4(A8 * g, 0.f, 0.f, 0.f);
}

// ---------------------------------------------------------------------------
// Shared per-tile step body (R6-proven, verbatim semantics).
// ---------------------------------------------------------------------------
__device__ __forceinline__ void step_tile(
    const float* __restrict__ src, const float* __restrict__ A,
    const float* __restrict__ hinv, float* __restrict__ dst,
    float4* tile, float* lse_s,
    int th0, int tw0, int t, int sub, int pr, int pc0) {
  int pix0 = (th0 + pr) * WW + (tw0 + pc0);
  int pix1 = pix0 + 1;

  // ---- Phase 1a: issue halo staging loads -------------------------------
  float4 vx[12];
  bool stager = (t < NHALO);
  if (stager) {
    int r = t / HW_HALO;
    int c = t - r * HW_HALO;
    int gh = (th0 + r - 1) & (HH - 1);       // periodic wrap
    int gw = (tw0 + c - 1) & (WW - 1);
    const float4* sp = (const float4*)src + (size_t)(gh * WW + gw) * 12;
#pragma unroll
    for (int i = 0; i < 12; i++) vx[i] = sp[i];
  }

  // ---- Phase 1b: prefetch packed stencil weights + hinv -----------------
  const float4* ap0 = (const float4*)A + (size_t)pix0 * 3;
  const float4* ap1 = (const float4*)A + (size_t)pix1 * 3;
  float4 wA0 = ap0[0], wB0 = ap0[1], wC0 = ap0[2];
  float4 wA1 = ap1[0], wB1 = ap1[1], wC1 = ap1[2];
  const float2* hp = (const float2*)(hinv + (size_t)pix0 * 3);
  float2 h01 = hp[0], h23 = hp[1], h45 = hp[2];

  // ---- Phase 1c: lse (parallel chains) + LDS staging writes -------------
  if (stager) {
    float4 mv = vx[0];
#pragma unroll
    for (int i = 1; i < 12; i++) {
      mv.x = fmaxf(mv.x, vx[i].x); mv.y = fmaxf(mv.y, vx[i].y);
      mv.z = fmaxf(mv.z, vx[i].z); mv.w = fmaxf(mv.w, vx[i].w);
    }
    float m = fmaxf(fmaxf(mv.x, mv.y), fmaxf(mv.z, mv.w));
    float sx = 0.f, sy = 0.f, sz = 0.f, sw = 0.f;
#pragma unroll
    for (int i = 0; i < 12; i++) {
      sx += __expf(vx[i].x - m); sy += __expf(vx[i].y - m);
      sz += __expf(vx[i].z - m); sw += __expf(vx[i].w - m);
      tile[t * PSTRIDE + i] = vx[i];
    }
    lse_s[t] = m + __logf((sx + sy) + (sz + sw));
  }
  __syncthreads();

  // ---- Phase 2: pixel-pair compute --------------------------------------
  float wt0[9] = {wA0.x, wA0.y, wA0.z, wA0.w, wB0.x, wB0.y, wB0.z, wB0.w, wC0.x};
  float wt1[9] = {wA1.x, wA1.y, wA1.z, wA1.w, wB1.x, wB1.y, wB1.z, wB1.w, wC1.x};
  float ha0 = h01.x, hc0 = h01.y, hb0 = h23.x;
  float ha1 = h23.y, hc1 = h45.x, hb1 = h45.y;

  int lc0 = (pr + 1) * HW_HALO + (pc0 + 1);
  float l0C = lse_s[lc0];
  float l0R = lse_s[lc0 + 1];                 // = l1C
  float l1R = lse_s[lc0 + 2];
  float l0D = lse_s[lc0 + HW_HALO];
  float l1D = lse_s[lc0 + HW_HALO + 1];
  float dld0 = l0C - l0D, dlr0 = l0C - l0R;
  float dld1 = l0R - l1D, dlr1 = l0R - l1R;

  int poff[3][4];
#pragma unroll
  for (int dr = 0; dr < 3; dr++)
#pragma unroll
    for (int dc = 0; dc < 4; dc++)
      poff[dr][dc] = ((pr + dr) * HW_HALO + pc0 + dc) * PSTRIDE;

  float4 vals0[3], vals1[3];
  float sum0 = 0.f, sum1 = 0.f;
#pragma unroll
  for (int j = 0; j < 3; j++) {
    int ch = j * 4 + sub;
    float4 q[3][4];
#pragma unroll
    for (int dr = 0; dr < 3; dr++)
#pragma unroll
      for (int dc = 0; dc < 4; dc++) q[dr][dc] = tile[poff[dr][dc] + ch];

    float4 val0, val1;
#define COMP(f)                                                                \
    {                                                                          \
      float s0_ = wt0[0] * q[0][0].f + wt0[1] * q[0][1].f + wt0[2] * q[0][2].f \
                + wt0[3] * q[1][0].f + wt0[4] * q[1][1].f + wt0[5] * q[1][2].f \
                + wt0[6] * q[2][0].f + wt0[7] * q[2][1].f + wt0[8] * q[2][2].f;\
      float v00 = q[2][1].f - q[1][1].f + dld0;                                \
      float v10 = q[1][2].f - q[1][1].f + dlr0;                                \
      float vv0 = s0_ + 0.5f * (ha0 * v00 * v00 + hc0 * v10 * v10) +           \
                  hb0 * (v00 * v10);                                           \
      val0.f = vv0; sum0 += vv0;                                               \
      float s1_ = wt1[0] * q[0][1].f + wt1[1] * q[0][2].f + wt1[2] * q[0][3].f \
                + wt1[3] * q[1][1].f + wt1[4] * q[1][2].f + wt1[5] * q[1][3].f \
                + wt1[6] * q[2][1].f + wt1[7] * q[2][2].f + wt1[8] * q[2][3].f;\
      float v01 = q[2][2].f - q[1][2].f + dld1;                                \
      float v11 = q[1][3].f - q[1][2].f + dlr1;                                \
      float vv1 = s1_ + 0.5f * (ha1 * v01 * v01 + hc1 * v11 * v11) +           \
                  hb1 * (v01 * v11);                                           \
      val1.f = vv1; sum1 += vv1;                                               \
    }
    COMP(x) COMP(y) COMP(z) COMP(w)
#undef COMP
    vals0[j] = val0;
    vals1[j] = val1;
  }

  sum0 += __shfl_xor(sum0, 1); sum0 += __shfl_xor(sum0, 2);
  sum1 += __shfl_xor(sum1, 1); sum1 += __shfl_xor(sum1, 2);
  float mean0 = sum0 * (1.0f / 48.0f);
  float mean1 = sum1 * (1.0f / 48.0f);

  int cen0 = lc0 * PSTRIDE;
  float4* op0 = (float4*)(dst + (size_t)pix0 * NCH);
  float4* op1 = op0 + 12;
#pragma unroll
  for (int j = 0; j < 3; j++) {
    int ch = j * 4 + sub;
    float4 c0 = tile[cen0 + ch];
    float4 c1 = tile[cen0 + PSTRIDE + ch];
    float4 r0, r1;
    r0.x = c0.x + 0.2f * fminf(fmaxf(vals0[j].x - mean0, -1e8f), 1e8f);
    r0.y = c0.y + 0.2f * fminf(fmaxf(vals0[j].y - mean0, -1e8f), 1e8f);
    r0.z = c0.z + 0.2f * fminf(fmaxf(vals0[j].z - mean0, -1e8f), 1e8f);
    r0.w = c0.w + 0.2f * fminf(fmaxf(vals0[j].w - mean0, -1e8f), 1e8f);
    r1.x = c1.x + 0.2f * fminf(fmaxf(vals1[j].x - mean1, -1e8f), 1e8f);
    r1.y = c1.y + 0.2f * fminf(fmaxf(vals1[j].y - mean1, -1e8f), 1e8f);
    r1.z = c1.z + 0.2f * fminf(fmaxf(vals1[j].z - mean1, -1e8f), 1e8f);
    r1.w = c1.w + 0.2f * fminf(fmaxf(vals1[j].w - mean1, -1e8f), 1e8f);
    op0[ch] = r0;
    op1[ch] = r1;
  }
}

// ---------------------------------------------------------------------------
// Fallback: single Euler step per launch (R6-proven, 209.8 us total).
// ---------------------------------------------------------------------------
__global__ __launch_bounds__(256, 4) void step_fused_kernel(
    const float* __restrict__ x, const float* __restrict__ A,
    const float* __restrict__ hinv, float* __restrict__ xn) {
  __shared__ float4 tile[NHALO * PSTRIDE];   // 37,440 B
  __shared__ float lse_s[NHALO];             // + 720 B

  int b = blockIdx.x;
  int tile_id = (b & 7) * 256 + (b >> 3);    // XCD-band swizzle
  int th0 = (tile_id >> 5) * TH;
  int tw0 = (tile_id & 31) * TW;

  int t = threadIdx.x;
  int sub = t & 3;
  int pair = t >> 2;
  int pr = pair >> 3;
  int pc0 = (pair & 7) * 2;

  step_tile(x, A, hinv, xn, tile, lse_s, th0, tw0, t, sub, pr, pc0);
}

// ---------------------------------------------------------------------------
// Cooperative persistent kernel: all 5 Euler steps in one launch.
// Grid-strided (any grid size); grid.sync + __threadfence at step boundaries
// (release: L2 writeback; acquire: invalidate stale cross-XCD lines).
// ---------------------------------------------------------------------------
__global__ __launch_bounds__(256, 4) void multi_step_kernel(
    const float* __restrict__ v, const float* __restrict__ A,
    const float* __restrict__ hinv, float* __restrict__ out,
    float* __restrict__ xbuf) {
  cg::grid_group grid = cg::this_grid();
  __shared__ float4 tile[NHALO * PSTRIDE];
  __shared__ float lse_s[NHALO];

  int t = threadIdx.x;
  int sub = t & 3;
  int pair = t >> 2;
  int pr = pair >> 3;
  int pc0 = (pair & 7) * 2;

  const float* src = v;
  float* dst = out;

  for (int s = 0; s < 5; ++s) {
    for (int vb = blockIdx.x; vb < NTILES; vb += gridDim.x) {
      int tile_id = (vb & 7) * 256 + (vb >> 3);  // XCD-band swizzle
      int th0 = (tile_id >> 5) * TH;
      int tw0 = (tile_id & 31) * TW;
      step_tile(src, A, hinv, dst, tile, lse_s, th0, tw0, t, sub, pr, pc0);
      __syncthreads();   // LDS reuse guard before next tile's staging
    }

    if (s < 4) {
      __threadfence();   // release: write back dirty L2 lines
      grid.sync();
      __threadfence();   // acquire: invalidate stale copies
    }
    int ns = s + 1;
    src = (ns & 1) ? out : xbuf;
    dst = (ns & 1) ? xbuf : out;
  }
}

// ---------------------------------------------------------------------------
// Host launcher.  inputs: v (H,W,48), Dt (H,W,3), dg (H,W,1), hinv (H,W,3)
// ws layout: A[12*HW packed] | xbuf[HW*48]   (~63 MB)
// Launch policy (R7 post-mortem: cooperative@1024 was refused -> zeros):
//   - query cooperative-launch attr + occupancy (pure host queries)
//   - if occupancy says <=3 blocks/CU co-residency, launch cooperative at
//     maxB*256 (<=768) -- never again demand the zero-margin 4/CU=1024
//   - if occupancy says >=4/CU, R7's size hypothesis is falsified -> suspect
//     capture incompatibility -> skip cooperative entirely
//   - any refusal (error-checked) falls back to the proven 5-launch path
// ---------------------------------------------------------------------------
extern "C" void kernel_launch(void* const* d_in, const int* in_sizes, int n_in,
                              void* d_out, int out_size, void* d_ws, size_t ws_size,
                              hipStream_t stream) {
  const float* v    = (const float*)d_in[0];
  const float* Dt   = (const float*)d_in[1];
  const float* dg   = (const float*)d_in[2];
  const float* hinv = (const float*)d_in[3];
  float* out = (float*)d_out;

  float* A    = (float*)d_ws;
  float* xbuf = A + (size_t)ASTRIDE * HWPIX;

  compute_A_kernel<<<dim3(HWPIX / 256), dim3(256), 0, stream>>>(Dt, dg, A);

  bool coop_done = false;
  int coopAttr = 0, dev = 0;
  (void)hipGetDevice(&dev);
  (void)hipDeviceGetAttribute(&coopAttr, hipDeviceAttributeCooperativeLaunch, dev);
  if (coopAttr) {
    int maxB = 0;
    hipError_t qe = hipOccupancyMaxActiveBlocksPerMultiprocessor(
        &maxB, (const void*)multi_step_kernel, 256, 0);
    if (qe == hipSuccess && maxB >= 1 && maxB <= 3) {
      int nb = maxB * 256;                     // 256 CUs on MI355X
      const float* vv = v;
      const float* AA = A;
      const float* hh = hinv;
      float* oo = out;
      float* xb = xbuf;
      void* args[] = {(void*)&vv, (void*)&AA, (void*)&hh, (void*)&oo, (void*)&xb};
      hipError_t e = hipLaunchCooperativeKernel((void*)multi_step_kernel,
                                                dim3(nb), dim3(256), args, 0,
                                                stream);
      if (e == hipSuccess) coop_done = true;
      else (void)hipGetLastError();            // clear sticky error
    } else if (qe != hipSuccess) {
      (void)hipGetLastError();
    }
    // maxB >= 4: R7 tried exactly that and was refused -> don't re-poke.
  }

  if (!coop_done) {
    const float* cur = v;
    float* nxt = out;
    for (int s = 0; s < 5; s++) {
      step_fused_kernel<<<dim3(HWPIX / 128), dim3(256), 0, stream>>>(
          cur, A, hinv, nxt);
      if (s == 0) {
        cur = out;
        nxt = xbuf;
      } else {
        float* t = (float*)cur;
        cur = nxt;
        nxt = t;
      }
    }
  }
}

// Round 9
// 215.396 us; speedup vs baseline: 3.9493x; 3.9493x over previous
//
#include <hip/hip_runtime.h>
#include <math.h>

#define HH 512
#define WW 512
#define NCH 48
#define HWPIX (HH * WW)

#define TW 16            // tile width (pixels)
#define TH 16            // tile height
#define HW_HALO 18       // TW + 2
#define HH_HALO 18       // TH + 2
#define NHALO (HW_HALO * HH_HALO)   // 324 halo pixels
#define PSTRIDE 13       // float4 slots per halo pixel (12 + 1 pad)
#define ASTRIDE 12       // floats per pixel in packed A (9 + 3 pad, 16B-aligned)
#define NBLOCKS (HWPIX / 256)       // 1024 tiles of 16x16

// ---------------------------------------------------------------------------
// Kernel 1: precompute the 9 per-pixel stencil weights from Dt, with
//   border masks, 1/dg and MSQ=0.1 folded in.  Pixel-major packed layout:
//   A[pix*12 + k] multiplies x[h-1+k/3, w-1+k%3]; 3 aligned float4 per pixel.
// ---------------------------------------------------------------------------
__global__ __launch_bounds__(256) void compute_A_kernel(
    const float* __restrict__ Dt, const float* __restrict__ dg,
    float* __restrict__ A) {
  int pix = blockIdx.x * blockDim.x + threadIdx.x;
  int h = pix >> 9;
  int w = pix & (WW - 1);
  int hm = (h == 0) ? HH - 1 : h - 1;
  int hp = (h == HH - 1) ? 0 : h + 1;
  int wm = (w == 0) ? WW - 1 : w - 1;
  int wp = (w == WW - 1) ? 0 : w + 1;

  float aC, cC, bC, cL, bL, cR, bR, aU, bU, aD, bD;
  float bUL, bUR, bDL, bDR;
  {
    int p;
    p = (h * WW + w) * 3;   aC = Dt[p]; cC = Dt[p + 1]; bC = Dt[p + 2];
    p = (h * WW + wm) * 3;  cL = Dt[p + 1]; bL = Dt[p + 2];
    p = (h * WW + wp) * 3;  cR = Dt[p + 1]; bR = Dt[p + 2];
    p = (hm * WW + w) * 3;  aU = Dt[p]; bU = Dt[p + 2];
    p = (hp * WW + w) * 3;  aD = Dt[p]; bD = Dt[p + 2];
    p = (hm * WW + wm) * 3; bUL = Dt[p + 2];
    p = (hm * WW + wp) * 3; bUR = Dt[p + 2];
    p = (hp * WW + wm) * 3; bDL = Dt[p + 2];
    p = (hp * WW + wp) * 3; bDR = Dt[p + 2];
  }

  float A0 = (fabsf(bDL) - bDL + fabsf(bC) - bC) * 0.25f;
  float A1 = (cL + cC - fabsf(bL) - fabsf(bC)) * 0.5f;
  float A2 = (fabsf(bUL) + bUL + fabsf(bC) + bC) * 0.25f;
  float A3 = (aD + aC - fabsf(bD) - fabsf(bC)) * 0.5f;
  float A4 = -(aD + 2.f * aC + aU) * 0.5f
             - (fabsf(bDL) - bDL + fabsf(bUL) + bUL) * 0.25f
             - (fabsf(bDR) + bDR + fabsf(bUR) - bUR) * 0.25f
             + (fabsf(bD) + fabsf(bU) + fabsf(bR) + fabsf(bL) + 2.f * fabsf(bC)) * 0.5f
             - (cR + 2.f * cC + cL) * 0.5f;
  float A5 = (aU + aC - fabsf(bU) - fabsf(bC)) * 0.5f;
  float A6 = (fabsf(bDR) + bDR + fabsf(bC) + bC) * 0.25f;
  float A7 = (cR + cC - fabsf(bR) - fabsf(bC)) * 0.5f;
  float A8 = (fabsf(bUR) - bUR + fabsf(bC) - bC) * 0.25f;

  bool ru = (h > 0), rd = (h < HH - 1), cl = (w > 0), cr = (w < WW - 1);
  if (!(ru && cl)) A0 = 0.f;
  if (!ru)         A1 = 0.f;
  if (!(ru && cr)) A2 = 0.f;
  if (!cl)         A3 = 0.f;
  if (!cr)         A5 = 0.f;
  if (!(rd && cl)) A6 = 0.f;
  if (!rd)         A7 = 0.f;
  if (!(rd && cr)) A8 = 0.f;

  float g = 1.0f / dg[pix];
  float4* Ao = (float4*)A + (size_t)pix * 3;
  Ao[0] = make_float4(A0 * g, A1 * g, A2 * g, A3 * g);
  Ao[1] = make_float4(A4 * g + 0.1f, A5 * g, A6 * g, A7 * g);
  Ao[2] = make_float4(A8 * g, 0.f, 0.f, 0.f);
}

// ---------------------------------------------------------------------------
// Fused Euler step, 16x16 tile (R9: was 16x8 — halo over-fetch 1.41x -> 1.27x,
// reads -7 MB/step; structure otherwise identical to the proven R6 kernel).
// 512-thread blocks: 324 stagers (one halo pixel each), 128 quads = 256 px.
// LDS 68.7 KB -> 2 blocks/CU = 16 waves/CU (same occupancy as R6; VGPR
// capped at 128 by __launch_bounds__(512,4)).
// Phase 1: stagers load 12 float4 (periodic wrap) into LDS AND compute the
//   48-ch logsumexp in-register (load/exp interleave = the latency hiding;
//   R5 lesson: pure-DMA staging with no own-thread work was +6 us/step).
//   A (3x float4) + hinv (3x float2) prefetched pre-barrier.
// Phase 2: quad handles a horizontally-adjacent pixel pair; 3x4 LDS patch
//   serves both 3x3 stencils; quad-shuffle channel mean; clipped update.
// XCD-band swizzle: XCD k (= b%8) gets 4 tile rows = pixel rows [64k,64k+64).
// ---------------------------------------------------------------------------
__global__ __launch_bounds__(512, 4) void step_fused_kernel(
    const float* __restrict__ x, const float* __restrict__ A,
    const float* __restrict__ hinv, float* __restrict__ xn) {
  __shared__ float4 tile[NHALO * PSTRIDE];   // 324*13*16 = 67,392 B
  __shared__ float lse_s[NHALO];             // + 1,296 B

  int b = blockIdx.x;
  int tile_id = (b & 7) * 128 + (b >> 3);    // 1024 tiles, 32 rows x 32 cols
  int th0 = (tile_id >> 5) * TH;
  int tw0 = (tile_id & 31) * TW;

  int t = threadIdx.x;
  int sub = t & 3;                            // interleaved chunk set
  int pair = t >> 2;                          // 0..127
  int pr = pair >> 3;                         // tile row 0..15
  int pc0 = (pair & 7) * 2;                   // even tile col 0..14
  int pix0 = (th0 + pr) * WW + (tw0 + pc0);
  int pix1 = pix0 + 1;

  // ---- Phase 1a: issue halo staging loads (feeds lse + LDS) -------------
  float4 v[12];
  bool stager = (t < NHALO);
  if (stager) {
    int r = t / HW_HALO;
    int c = t - r * HW_HALO;
    int gh = (th0 + r - 1) & (HH - 1);       // periodic wrap
    int gw = (tw0 + c - 1) & (WW - 1);
    const float4* src = (const float4*)x + (size_t)(gh * WW + gw) * 12;
#pragma unroll
    for (int i = 0; i < 12; i++) v[i] = src[i];
  }

  // ---- Phase 1b: prefetch packed stencil weights + hinv (pre-barrier) ----
  const float4* ap0 = (const float4*)A + (size_t)pix0 * 3;
  const float4* ap1 = (const float4*)A + (size_t)pix1 * 3;
  float4 wA0 = ap0[0], wB0 = ap0[1], wC0 = ap0[2];
  float4 wA1 = ap1[0], wB1 = ap1[1], wC1 = ap1[2];
  // 6 consecutive floats for the pair; pix0 is even so base is 8B-aligned
  const float2* hp = (const float2*)(hinv + (size_t)pix0 * 3);
  float2 h01 = hp[0], h23 = hp[1], h45 = hp[2];

  // ---- Phase 1c: lse (parallel chains) + LDS staging writes -------------
  if (stager) {
    float4 mv = v[0];
#pragma unroll
    for (int i = 1; i < 12; i++) {
      mv.x = fmaxf(mv.x, v[i].x); mv.y = fmaxf(mv.y, v[i].y);
      mv.z = fmaxf(mv.z, v[i].z); mv.w = fmaxf(mv.w, v[i].w);
    }
    float m = fmaxf(fmaxf(mv.x, mv.y), fmaxf(mv.z, mv.w));
    float sx = 0.f, sy = 0.f, sz = 0.f, sw = 0.f;
#pragma unroll
    for (int i = 0; i < 12; i++) {
      sx += __expf(v[i].x - m); sy += __expf(v[i].y - m);
      sz += __expf(v[i].z - m); sw += __expf(v[i].w - m);
      tile[t * PSTRIDE + i] = v[i];
    }
    lse_s[t] = m + __logf((sx + sy) + (sz + sw));
  }
  __syncthreads();

  // ---- Phase 2: pixel-pair compute --------------------------------------
  float wt0[9] = {wA0.x, wA0.y, wA0.z, wA0.w, wB0.x, wB0.y, wB0.z, wB0.w, wC0.x};
  float wt1[9] = {wA1.x, wA1.y, wA1.z, wA1.w, wB1.x, wB1.y, wB1.z, wB1.w, wC1.x};
  float ha0 = h01.x, hc0 = h01.y, hb0 = h23.x;
  float ha1 = h23.y, hc1 = h45.x, hb1 = h45.y;

  // lse taps (halo coords: center of px0 = (pr+1, pc0+1))
  int lc0 = (pr + 1) * HW_HALO + (pc0 + 1);
  float l0C = lse_s[lc0];
  float l0R = lse_s[lc0 + 1];                 // = l1C
  float l1R = lse_s[lc0 + 2];
  float l0D = lse_s[lc0 + HW_HALO];
  float l1D = lse_s[lc0 + HW_HALO + 1];
  float dld0 = l0C - l0D, dlr0 = l0C - l0R;
  float dld1 = l0R - l1D, dlr1 = l0R - l1R;

  // LDS float4-offsets of the 3x4 patch (rows pr..pr+2, cols pc0..pc0+3)
  int poff[3][4];
#pragma unroll
  for (int dr = 0; dr < 3; dr++)
#pragma unroll
    for (int dc = 0; dc < 4; dc++)
      poff[dr][dc] = ((pr + dr) * HW_HALO + pc0 + dc) * PSTRIDE;

  float4 vals0[3], vals1[3];
  float sum0 = 0.f, sum1 = 0.f;
#pragma unroll
  for (int j = 0; j < 3; j++) {
    int ch = j * 4 + sub;
    float4 q[3][4];
#pragma unroll
    for (int dr = 0; dr < 3; dr++)
#pragma unroll
      for (int dc = 0; dc < 4; dc++) q[dr][dc] = tile[poff[dr][dc] + ch];

    float4 val0, val1;
#define COMP(f)                                                                \
    {                                                                          \
      float s0_ = wt0[0] * q[0][0].f + wt0[1] * q[0][1].f + wt0[2] * q[0][2].f \
                + wt0[3] * q[1][0].f + wt0[4] * q[1][1].f + wt0[5] * q[1][2].f \
                + wt0[6] * q[2][0].f + wt0[7] * q[2][1].f + wt0[8] * q[2][2].f;\
      float v00 = q[2][1].f - q[1][1].f + dld0;                                \
      float v10 = q[1][2].f - q[1][1].f + dlr0;                                \
      float vv0 = s0_ + 0.5f * (ha0 * v00 * v00 + hc0 * v10 * v10) +           \
                  hb0 * (v00 * v10);                                           \
      val0.f = vv0; sum0 += vv0;                                               \
      float s1_ = wt1[0] * q[0][1].f + wt1[1] * q[0][2].f + wt1[2] * q[0][3].f \
                + wt1[3] * q[1][1].f + wt1[4] * q[1][2].f + wt1[5] * q[1][3].f \
                + wt1[6] * q[2][1].f + wt1[7] * q[2][2].f + wt1[8] * q[2][3].f;\
      float v01 = q[2][2].f - q[1][2].f + dld1;                                \
      float v11 = q[1][3].f - q[1][2].f + dlr1;                                \
      float vv1 = s1_ + 0.5f * (ha1 * v01 * v01 + hc1 * v11 * v11) +           \
                  hb1 * (v01 * v11);                                           \
      val1.f = vv1; sum1 += vv1;                                               \
    }
    COMP(x) COMP(y) COMP(z) COMP(w)
#undef COMP
    vals0[j] = val0;
    vals1[j] = val1;
  }

  // channel mean across the 4-thread quad (48 channels per pixel)
  sum0 += __shfl_xor(sum0, 1); sum0 += __shfl_xor(sum0, 2);
  sum1 += __shfl_xor(sum1, 1); sum1 += __shfl_xor(sum1, 2);
  float mean0 = sum0 * (1.0f / 48.0f);
  float mean1 = sum1 * (1.0f / 48.0f);

  // centers re-read from LDS (saves 24 VGPRs vs holding them live)
  int cen0 = lc0 * PSTRIDE;                   // px0 center halo offset
  float4* op0 = (float4*)(xn + (size_t)pix0 * NCH);
  float4* op1 = op0 + 12;
#pragma unroll
  for (int j = 0; j < 3; j++) {
    int ch = j * 4 + sub;
    float4 c0 = tile[cen0 + ch];
    float4 c1 = tile[cen0 + PSTRIDE + ch];
    float4 r0, r1;
    r0.x = c0.x + 0.2f * fminf(fmaxf(vals0[j].x - mean0, -1e8f), 1e8f);
    r0.y = c0.y + 0.2f * fminf(fmaxf(vals0[j].y - mean0, -1e8f), 1e8f);
    r0.z = c0.z + 0.2f * fminf(fmaxf(vals0[j].z - mean0, -1e8f), 1e8f);
    r0.w = c0.w + 0.2f * fminf(fmaxf(vals0[j].w - mean0, -1e8f), 1e8f);
    r1.x = c1.x + 0.2f * fminf(fmaxf(vals1[j].x - mean1, -1e8f), 1e8f);
    r1.y = c1.y + 0.2f * fminf(fmaxf(vals1[j].y - mean1, -1e8f), 1e8f);
    r1.z = c1.z + 0.2f * fminf(fmaxf(vals1[j].z - mean1, -1e8f), 1e8f);
    r1.w = c1.w + 0.2f * fminf(fmaxf(vals1[j].w - mean1, -1e8f), 1e8f);
    op0[ch] = r0;
    op1[ch] = r1;
  }
}

// ---------------------------------------------------------------------------
// Host launcher.  inputs: v (H,W,48), Dt (H,W,3), dg (H,W,1), hinv (H,W,3)
// ws layout: A[12*HW packed] | xbuf[HW*48]   (~63 MB)
// ping-pong: v -> out -> ws -> out -> ws -> out  (5 steps)
// (Cooperative path removed: R8 measured it at 4x slower — per-wave
//  threadfence L2 thrash + grid.sync latency.)
// ---------------------------------------------------------------------------
extern "C" void kernel_launch(void* const* d_in, const int* in_sizes, int n_in,
                              void* d_out, int out_size, void* d_ws, size_t ws_size,
                              hipStream_t stream) {
  const float* v    = (const float*)d_in[0];
  const float* Dt   = (const float*)d_in[1];
  const float* dg   = (const float*)d_in[2];
  const float* hinv = (const float*)d_in[3];
  float* out = (float*)d_out;

  float* A    = (float*)d_ws;
  float* xbuf = A + (size_t)ASTRIDE * HWPIX;

  compute_A_kernel<<<dim3(HWPIX / 256), dim3(256), 0, stream>>>(Dt, dg, A);

  const float* cur = v;
  float* nxt = out;
  for (int s = 0; s < 5; s++) {
    step_fused_kernel<<<dim3(NBLOCKS), dim3(512), 0, stream>>>(cur, A, hinv, nxt);
    if (s == 0) {
      cur = out;
      nxt = xbuf;
    } else {
      float* t = (float*)cur;
      cur = nxt;
      nxt = t;
    }
  }
}